// Round 21
// baseline (362.156 us; speedup 1.0000x reference)
//
#include <hip/hip_runtime.h>
#include <math.h>

#define NNODES 50000
#define NEDGES 800000
#define D 128
#define NEG_SLOPE 0.2f
#define BN_EPS 1e-5f
#define SCAN_THREADS 1024
#define WAVE_REGION 3328                      // 52 elems x 64 lanes
#define COUNTS_PAD (16 * WAVE_REGION)         // 53248 >= 50000
#define DSUB 64                               // sub-slots per degree value
#define DBINS (128 * DSUB)                    // 8192 bins
#define SUM_SLOTS 64
#define NB_NODE 196                           // ceil(50000/256)
#define NB_EDGE 3125                          // 800000/256
#define NB_X    3125                          // 800000 ushort8 groups /256

typedef __attribute__((ext_vector_type(8))) unsigned short ushort8_t;
typedef __attribute__((ext_vector_type(8))) short bf16x8;
typedef __attribute__((ext_vector_type(4))) float f32x4;

// RNE float -> bf16
__device__ __forceinline__ unsigned short f2bf(float x) {
  unsigned u = __float_as_uint(x);
  u += 0x7fffu + ((u >> 16) & 1u);
  return (unsigned short)(u >> 16);
}
__device__ __forceinline__ float bf2f(unsigned short h) {
  return __uint_as_float((unsigned)h << 16);
}

// ============ CSR build (once per call) ====================================
// rank[e] = position of edge e among edges with the same dst (atomic order).
__global__ __launch_bounds__(256) void k_rank(const int* __restrict__ dst,
        int* __restrict__ counts, int* __restrict__ rank, int E) {
  int e = blockIdx.x * 256 + threadIdx.x;
  if (e < E) rank[e] = atomicAdd(&counts[dst[e]], 1);
}

// Multi-block degree histogram, sub-slotted (chain depth ~80).
__global__ __launch_bounds__(256) void k_deg_hist(const int* __restrict__ counts,
        int* __restrict__ dhist, int n) {
  int i = blockIdx.x * 256 + threadIdx.x;
  if (i >= n) return;
  int d = counts[i];
  if (d > 127) d = 127;
  atomicAdd(&dhist[((127 - d) << 6) | (i & (DSUB - 1))], 1);
}

// Single-WG: row_ptr prefix scan (wave-coalesced) + 8192-bin exclusive scan.
__global__ __launch_bounds__(1024) void k_scan_sort(const int* __restrict__ counts,
        const int* __restrict__ dhist, int* __restrict__ row_ptr,
        int* __restrict__ dcur, int n) {
  __shared__ int wtot[16];
  int t = threadIdx.x;
  int lane = t & 63, w = t >> 6;
  int rb = w * WAVE_REGION;
  int tot = 0;
  for (int j = 0; j < 52; ++j) tot += counts[rb + j * 64 + lane];
#pragma unroll
  for (int d = 1; d < 64; d <<= 1) tot += __shfl_xor(tot, d);
  if (lane == 0) wtot[w] = tot;
  __syncthreads();
  int wbase = 0;
#pragma unroll
  for (int i = 0; i < 16; ++i) wbase += (i < w) ? wtot[i] : 0;
  int running = wbase;
  for (int j = 0; j < 52; ++j) {
    int idx = rb + j * 64 + lane;
    int v = counts[idx];
    int incl = v;
#pragma unroll
    for (int d = 1; d < 64; d <<= 1) {
      int u = __shfl_up(incl, d);
      if (lane >= d) incl += u;
    }
    if (idx < n) row_ptr[idx + 1] = running + incl;
    running += __shfl(incl, 63);
  }
  if (t == 0) row_ptr[0] = 0;
  __syncthreads();
  int b8 = t * 8;
  int h[8];
  int ts = 0;
#pragma unroll
  for (int j = 0; j < 8; ++j) { h[j] = dhist[b8 + j]; ts += h[j]; }
  int incl = ts;
#pragma unroll
  for (int d = 1; d < 64; d <<= 1) {
    int u = __shfl_up(incl, d);
    if (lane >= d) incl += u;
  }
  if (lane == 63) wtot[w] = incl;
  __syncthreads();
  int wb2 = 0;
#pragma unroll
  for (int i = 0; i < 16; ++i) wb2 += (i < w) ? wtot[i] : 0;
  int ex = wb2 + incl - ts;
#pragma unroll
  for (int j = 0; j < 8; ++j) { dcur[b8 + j] = ex; ex += h[j]; }
}

// ============ merged setup: LPT place + CSR place + converts ===============
__global__ __launch_bounds__(256) void k_setup(const int* __restrict__ src,
        const int* __restrict__ dst, const int* __restrict__ rank,
        const int* __restrict__ row_ptr, const int* __restrict__ counts,
        int* __restrict__ dcur, int* __restrict__ node_order,
        int* __restrict__ col_src, const float* __restrict__ x,
        const float* __restrict__ Wl, const float* __restrict__ Wr,
        unsigned short* __restrict__ xb, unsigned short* __restrict__ wt,
        int n, int E, int total8) {
  int b = blockIdx.x;
  if (b < NB_NODE) {
    int i = b * 256 + threadIdx.x;
    if (i >= n) return;
    int d = counts[i];
    if (d > 127) d = 127;
    int pos = atomicAdd(&dcur[((127 - d) << 6) | (i & (DSUB - 1))], 1);
    node_order[pos] = i;
  } else if (b < NB_NODE + NB_EDGE) {
    int e = (b - NB_NODE) * 256 + threadIdx.x;
    if (e >= E) return;
    col_src[row_ptr[dst[e]] + rank[e]] = src[e];
  } else if (b < NB_NODE + NB_EDGE + 6) {
    int ls = b - NB_NODE - NB_EDGE;       // layer*2 + side
    int l = ls >> 1, s = ls & 1;
    const float* W = (s ? Wr : Wl) + l * D * D;
    unsigned short* o = wt + ls * D * D;
    for (int it = 0; it < 64; ++it) {
      int idx = it * 256 + threadIdx.x;
      int k = idx >> 7, c = idx & 127;
      o[c * D + k] = f2bf(W[idx]);        // transposed, K-contiguous
    }
  } else {
    int i = (b - NB_NODE - NB_EDGE - 6) * 256 + threadIdx.x;
    if (i >= total8) return;
    float4 a = ((const float4*)x)[2 * i];
    float4 bb = ((const float4*)x)[2 * i + 1];
    uint4 pk;
    pk.x = (unsigned)f2bf(a.x) | ((unsigned)f2bf(a.y) << 16);
    pk.y = (unsigned)f2bf(a.z) | ((unsigned)f2bf(a.w) << 16);
    pk.z = (unsigned)f2bf(bb.x) | ((unsigned)f2bf(bb.y) << 16);
    pk.w = (unsigned)f2bf(bb.z) | ((unsigned)f2bf(bb.w) << 16);
    ((uint4*)xb)[i] = pk;
  }
}

// ============ GEMM: bf16 MFMA 16x16x32 =====================================
__global__ __launch_bounds__(256) void k_gemm(const unsigned short* __restrict__ xb,
        const unsigned short* __restrict__ wt,   // this layer: [2][128 col][128 k]
        unsigned short* __restrict__ xlb, unsigned short* __restrict__ xrb,
        float* __restrict__ sums64, int n) {
  __shared__ unsigned short xs[128 * 128];   // 32 KB
  const int t = threadIdx.x;
  const int row0 = blockIdx.x * 128;
  const unsigned short* __restrict__ W = wt + (size_t)blockIdx.y * (D * D);
  unsigned short* __restrict__ outp = blockIdx.y ? xrb : xlb;

  if (blockIdx.x == 0 && blockIdx.y == 0) {
#pragma unroll
    for (int i = 0; i < SUM_SLOTS; ++i) sums64[i * 256 + t] = 0.f;
  }

#pragma unroll
  for (int i = 0; i < 8; ++i) {
    int ci = i * 256 + t;          // 16B-chunk index 0..2047
    int lr = ci >> 4, p = ci & 15;
    int grow = row0 + lr;
    if (grow >= n) grow = n - 1;   // clamped rows are never stored
    int gp = p ^ (lr & 7);
    uint4 v = *(const uint4*)(xb + (size_t)grow * D + gp * 8);
    *(uint4*)((char*)xs + ci * 16) = v;
  }
  __syncthreads();

  const int lane = t & 63, wv = t >> 6;
  const int colg = lane & 15, kg = lane >> 4;

  f32x4 acc[2][8];
#pragma unroll
  for (int rr = 0; rr < 2; ++rr)
#pragma unroll
    for (int cc = 0; cc < 8; ++cc) acc[rr][cc] = (f32x4)(0.f);

#pragma unroll
  for (int ks = 0; ks < 4; ++ks) {
    bf16x8 a[2], b[8];
#pragma unroll
    for (int rr = 0; rr < 2; ++rr) {
      int lr = wv * 32 + rr * 16 + colg;
      int byte = (lr * 256 + ks * 64 + kg * 16) ^ ((lr & 7) << 4);
      a[rr] = *(const bf16x8*)((const char*)xs + byte);
    }
#pragma unroll
    for (int cc = 0; cc < 8; ++cc) {
      int col = cc * 16 + colg;
      b[cc] = *(const bf16x8*)(W + (size_t)col * D + ks * 32 + kg * 8);
    }
#pragma unroll
    for (int rr = 0; rr < 2; ++rr)
#pragma unroll
      for (int cc = 0; cc < 8; ++cc)
        acc[rr][cc] = __builtin_amdgcn_mfma_f32_16x16x32_bf16(a[rr], b[cc], acc[rr][cc], 0, 0, 0);
  }

#pragma unroll
  for (int rr = 0; rr < 2; ++rr) {
    int rbase = row0 + wv * 32 + rr * 16 + kg * 4;
#pragma unroll
    for (int cc = 0; cc < 8; ++cc) {
      int col = cc * 16 + colg;
      f32x4 v = acc[rr][cc];
#pragma unroll
      for (int r = 0; r < 4; ++r) {
        int grow = rbase + r;
        if (grow < n) outp[(size_t)grow * D + col] = f2bf(v[r]);
      }
    }
  }
}

// ============ fused score + softmax + aggregate + BN partials ==============
// No online-max: |e| <= sum|att_j|*|xl+xr| ~ 10 max, exp(e) safely inside
// f32 range (overflow at 88); per-node score spread <= ~40 -> denominator
// ratio <= e^40 << f32 max. Max-subtraction is mathematically a no-op on
// alpha, so dropping it removes the per-edge branch + rescale entirely.

__device__ __forceinline__ void agg_step(ushort8_t hv, const float* xrv,
        const float* atv, float& den, float* ac) {
  float v[8];
#pragma unroll
  for (int j = 0; j < 8; ++j) v[j] = bf2f(hv[j]);
  float p = 0.f;
#pragma unroll
  for (int j = 0; j < 8; ++j) {
    float tt = v[j] + xrv[j];
    tt = tt > 0.f ? tt : NEG_SLOPE * tt;
    p += tt * atv[j];
  }
  p += __shfl_xor(p, 1);
  p += __shfl_xor(p, 2);
  p += __shfl_xor(p, 4);
  p += __shfl_xor(p, 8);
  float a = __expf(p);
  den += a;
#pragma unroll
  for (int j = 0; j < 8; ++j) ac[j] += a * v[j];
}

__global__ __launch_bounds__(256) void k_agg(const unsigned short* __restrict__ xlb,
        const unsigned short* __restrict__ xrb, const int* __restrict__ col_src,
        const int* __restrict__ row_ptr, const int* __restrict__ node_order,
        const float* __restrict__ att, float* __restrict__ out,
        float* __restrict__ sums64, int n) {
  __shared__ float lsum[16][128];
  __shared__ float lsq[16][128];
  int g = blockIdx.x * 16 + (threadIdx.x >> 4);
  int grp = threadIdx.x >> 4;
  int lane = threadIdx.x & 15;
  bool active = (g < n);
  float r[8];
#pragma unroll
  for (int j = 0; j < 8; ++j) r[j] = 0.f;

  if (active) {
    int node = node_order[g];
    int ro = lane * 2;
    ushort8_t hr = ((const ushort8_t*)(xrb + (size_t)node * D))[lane];
    float xrv[8];
#pragma unroll
    for (int j = 0; j < 8; ++j) xrv[j] = bf2f(hr[j]);
    float4 at0 = ((const float4*)att)[ro];
    float4 at1 = ((const float4*)att)[ro + 1];
    float atv[8] = {at0.x, at0.y, at0.z, at0.w, at1.x, at1.y, at1.z, at1.w};

    int k0 = row_ptr[node], k1 = row_ptr[node + 1];
    float den = 0.f;
    float ac[8];
#pragma unroll
    for (int j = 0; j < 8; ++j) ac[j] = 0.f;

    const ushort8_t* xl8 = (const ushort8_t*)xlb;
    int k = k0;
    for (; k + 8 <= k1; k += 8) {
      int s0 = col_src[k],     s1 = col_src[k + 1], s2 = col_src[k + 2], s3 = col_src[k + 3];
      int s4 = col_src[k + 4], s5 = col_src[k + 5], s6 = col_src[k + 6], s7 = col_src[k + 7];
      ushort8_t h0 = xl8[(size_t)s0 * 16 + lane];
      ushort8_t h1 = xl8[(size_t)s1 * 16 + lane];
      ushort8_t h2 = xl8[(size_t)s2 * 16 + lane];
      ushort8_t h3 = xl8[(size_t)s3 * 16 + lane];
      ushort8_t h4 = xl8[(size_t)s4 * 16 + lane];
      ushort8_t h5 = xl8[(size_t)s5 * 16 + lane];
      ushort8_t h6 = xl8[(size_t)s6 * 16 + lane];
      ushort8_t h7 = xl8[(size_t)s7 * 16 + lane];
      agg_step(h0, xrv, atv, den, ac);
      agg_step(h1, xrv, atv, den, ac);
      agg_step(h2, xrv, atv, den, ac);
      agg_step(h3, xrv, atv, den, ac);
      agg_step(h4, xrv, atv, den, ac);
      agg_step(h5, xrv, atv, den, ac);
      agg_step(h6, xrv, atv, den, ac);
      agg_step(h7, xrv, atv, den, ac);
    }
    if (k + 4 <= k1) {
      int s0 = col_src[k], s1 = col_src[k + 1], s2 = col_src[k + 2], s3 = col_src[k + 3];
      ushort8_t h0 = xl8[(size_t)s0 * 16 + lane];
      ushort8_t h1 = xl8[(size_t)s1 * 16 + lane];
      ushort8_t h2 = xl8[(size_t)s2 * 16 + lane];
      ushort8_t h3 = xl8[(size_t)s3 * 16 + lane];
      agg_step(h0, xrv, atv, den, ac);
      agg_step(h1, xrv, atv, den, ac);
      agg_step(h2, xrv, atv, den, ac);
      agg_step(h3, xrv, atv, den, ac);
      k += 4;
    }
    for (; k < k1; ++k) {
      int s = col_src[k];
      ushort8_t h = xl8[(size_t)s * 16 + lane];
      agg_step(h, xrv, atv, den, ac);
    }

    float inv = 1.f / (den + 1e-16f);
#pragma unroll
    for (int j = 0; j < 8; ++j) r[j] = ac[j] * inv;
    float4* o4 = (float4*)out;
    o4[(size_t)node * 32 + ro]     = make_float4(r[0], r[1], r[2], r[3]);
    o4[(size_t)node * 32 + ro + 1] = make_float4(r[4], r[5], r[6], r[7]);
  }

  // ---- BN partials: LDS reduce 16 rows, one atomic record per block ----
#pragma unroll
  for (int j = 0; j < 8; ++j) {
    lsum[grp][lane * 8 + j] = r[j];
    lsq[grp][lane * 8 + j] = r[j] * r[j];
  }
  __syncthreads();
  int t = threadIdx.x;
  float s = 0.f;
  if (t < 128) {
#pragma unroll
    for (int gg = 0; gg < 16; ++gg) s += lsum[gg][t];
  } else {
#pragma unroll
    for (int gg = 0; gg < 16; ++gg) s += lsq[gg][t - 128];
  }
  atomicAdd(&sums64[(blockIdx.x & (SUM_SLOTS - 1)) * 256 + t], s);
}

// ============ BatchNorm finalize + apply (fused, grid-stride) ==============
__global__ __launch_bounds__(256) void k_bn_apply(const float* __restrict__ agg,
        const float* __restrict__ sums64, const float* __restrict__ gamma,
        const float* __restrict__ beta, float* __restrict__ xo,
        unsigned short* __restrict__ xbo, float inv_n, int total4, int last) {
  __shared__ float totl[256];
  __shared__ float ssl[256];
  int t = threadIdx.x;
  float a0 = 0.f, a1 = 0.f, a2 = 0.f, a3 = 0.f;
#pragma unroll
  for (int k = 0; k < SUM_SLOTS; k += 4) {
    a0 += sums64[(k + 0) * 256 + t];
    a1 += sums64[(k + 1) * 256 + t];
    a2 += sums64[(k + 2) * 256 + t];
    a3 += sums64[(k + 3) * 256 + t];
  }
  totl[t] = (a0 + a1) + (a2 + a3);
  __syncthreads();
  if (t < 128) {
    float mu = totl[t] * inv_n;
    float var = totl[128 + t] * inv_n - mu * mu;
    float rs = rsqrtf(var + BN_EPS);
    float sc = gamma[t] * rs;
    ssl[t] = sc;
    ssl[128 + t] = beta[t] - mu * sc;
  }
  __syncthreads();

  for (int i = blockIdx.x * 256 + t; i < total4; i += gridDim.x * 256) {
    float4 v = ((const float4*)agg)[i];
    int c4 = i & (D / 4 - 1);
    float4 sc = ((const float4*)ssl)[c4];
    float4 sh = ((const float4*)ssl)[D / 4 + c4];
    float y0 = sc.x * v.x + sh.x;
    float y1 = sc.y * v.y + sh.y;
    float y2 = sc.z * v.z + sh.z;
    float y3 = sc.w * v.w + sh.w;
    float4 g;
    g.x = 0.5f * y0 * (1.f + erff(y0 * 0.70710678118654752f));
    g.y = 0.5f * y1 * (1.f + erff(y1 * 0.70710678118654752f));
    g.z = 0.5f * y2 * (1.f + erff(y2 * 0.70710678118654752f));
    g.w = 0.5f * y3 * (1.f + erff(y3 * 0.70710678118654752f));
    if (last) {
      ((float4*)xo)[i] = g;
    } else {
      uint2 pk;
      pk.x = (unsigned)f2bf(g.x) | ((unsigned)f2bf(g.y) << 16);
      pk.y = (unsigned)f2bf(g.z) | ((unsigned)f2bf(g.w) << 16);
      ((uint2*)xbo)[i] = pk;
    }
  }
}

// ===========================================================================

extern "C" void kernel_launch(void* const* d_in, const int* in_sizes, int n_in,
                              void* d_out, int out_size, void* d_ws, size_t ws_size,
                              hipStream_t stream) {
  const float* x0    = (const float*)d_in[0];
  const int*   ei    = (const int*)d_in[1];
  const float* Wl    = (const float*)d_in[2];
  const float* Wr    = (const float*)d_in[3];
  const float* att   = (const float*)d_in[4];
  // d_in[5] = bias: cancelled exactly by BatchNorm mean-subtraction; unused.
  const float* gamma = (const float*)d_in[6];
  const float* beta  = (const float*)d_in[7];
  float* out = (float*)d_out;

  float* ws = (float*)d_ws;
  unsigned short* xb  = (unsigned short*)ws;              // [N][128] bf16
  unsigned short* xlb = (unsigned short*)(ws + 3200000);  // [N][128] bf16
  unsigned short* xrb = (unsigned short*)(ws + 6400000);  // [N][128] bf16
  int*   col_src    = (int*)(ws + 9600000);       //   800,000
  int*   rank       = (int*)(ws + 10400000);      //   800,000
  int*   row_ptr    = (int*)(ws + 11200000);      //    50,001
  int*   counts     = (int*)(ws + 11250004);      // COUNTS_PAD (53,248)
  int*   dhist      = (int*)(ws + 11303252);      //     8,192 (adjacent to counts)
  int*   dcur       = (int*)(ws + 11311444);      //     8,192
  int*   node_order = (int*)(ws + 11319636);      //    50,000
  float* sums64     = ws + 11369636;              //    16,384 (64 x 256)
  unsigned short* wt = (unsigned short*)(ws + 11386020);  // [3][2][128][128] bf16

  const int* src = ei;
  const int* dst = ei + NEDGES;

  // ---- one-time: CSR build + LPT sort + merged setup (5 dispatches) ----
  hipMemsetAsync(counts, 0, (COUNTS_PAD + DBINS) * sizeof(int), stream);  // counts+dhist
  k_rank<<<(NEDGES + 255) / 256, 256, 0, stream>>>(dst, counts, rank, NEDGES);
  k_deg_hist<<<(NNODES + 255) / 256, 256, 0, stream>>>(counts, dhist, NNODES);
  k_scan_sort<<<1, SCAN_THREADS, 0, stream>>>(counts, dhist, row_ptr, dcur, NNODES);
  k_setup<<<NB_NODE + NB_EDGE + 6 + NB_X, 256, 0, stream>>>(
      src, dst, rank, row_ptr, counts, dcur, node_order, col_src,
      x0, Wl, Wr, xb, wt, NNODES, NEDGES, NNODES * (D / 8));

  dim3 ggrid((NNODES + 127) / 128, 2);

  for (int l = 0; l < 3; ++l) {
    k_gemm<<<ggrid, 256, 0, stream>>>(xb, wt + (size_t)l * 2 * D * D, xlb, xrb,
                                      sums64, NNODES);

    // d_out is dead as an input after k_gemm -> safe to overwrite with agg.
    k_agg<<<(NNODES + 15) / 16, 256, 0, stream>>>(xlb, xrb, col_src, row_ptr,
                                                  node_order, att + l * D, out,
                                                  sums64, NNODES);

    k_bn_apply<<<512, 256, 0, stream>>>(out, sums64, gamma + l * D, beta + l * D,
                                        out, xb, 1.0f / NNODES,
                                        NNODES * (D / 4), l == 2 ? 1 : 0);
  }
}

// Round 22
// 350.427 us; speedup vs baseline: 1.0335x; 1.0335x over previous
//
#include <hip/hip_runtime.h>
#include <math.h>

#define NNODES 50000
#define NEDGES 800000
#define D 128
#define NEG_SLOPE 0.2f
#define BN_EPS 1e-5f
#define SCAN_THREADS 1024
#define WAVE_REGION 3328                      // 52 elems x 64 lanes
#define COUNTS_PAD (16 * WAVE_REGION)         // 53248 >= 50000
#define DSUB 64                               // sub-slots per degree value
#define DBINS (128 * DSUB)                    // 8192 bins
#define SUM_SLOTS 64
#define NB_NODE 196                           // ceil(50000/256)
#define NB_EDGE 3125                          // 800000/256
#define NB_X    3125                          // 800000 ushort8 groups /256

typedef __attribute__((ext_vector_type(8))) unsigned short ushort8_t;
typedef __attribute__((ext_vector_type(8))) short bf16x8;
typedef __attribute__((ext_vector_type(4))) float f32x4;

// RNE float -> bf16
__device__ __forceinline__ unsigned short f2bf(float x) {
  unsigned u = __float_as_uint(x);
  u += 0x7fffu + ((u >> 16) & 1u);
  return (unsigned short)(u >> 16);
}
__device__ __forceinline__ float bf2f(unsigned short h) {
  return __uint_as_float((unsigned)h << 16);
}

// ============ CSR build (once per call) ====================================
// rank[e] = position of edge e among edges with the same dst (atomic order).
// ~1 atomic/cycle/XCD + HBM write-through of returned sectors: at HW floor.
__global__ __launch_bounds__(256) void k_rank(const int* __restrict__ dst,
        int* __restrict__ counts, int* __restrict__ rank, int E) {
  int e = blockIdx.x * 256 + threadIdx.x;
  if (e < E) rank[e] = atomicAdd(&counts[dst[e]], 1);
}

// Multi-block degree histogram, sub-slotted (chain depth ~80, round-19 proven).
__global__ __launch_bounds__(256) void k_deg_hist(const int* __restrict__ counts,
        int* __restrict__ dhist, int n) {
  int i = blockIdx.x * 256 + threadIdx.x;
  if (i >= n) return;
  int d = counts[i];
  if (d > 127) d = 127;
  atomicAdd(&dhist[((127 - d) << 6) | (i & (DSUB - 1))], 1);
}

// Single-WG: row_ptr prefix scan (wave-coalesced) + 8192-bin exclusive scan.
__global__ __launch_bounds__(1024) void k_scan_sort(const int* __restrict__ counts,
        const int* __restrict__ dhist, int* __restrict__ row_ptr,
        int* __restrict__ dcur, int n) {
  __shared__ int wtot[16];
  int t = threadIdx.x;
  int lane = t & 63, w = t >> 6;
  int rb = w * WAVE_REGION;
  // ---- phase 1: scan counts -> row_ptr ----
  int tot = 0;
  for (int j = 0; j < 52; ++j) tot += counts[rb + j * 64 + lane];
#pragma unroll
  for (int d = 1; d < 64; d <<= 1) tot += __shfl_xor(tot, d);
  if (lane == 0) wtot[w] = tot;
  __syncthreads();
  int wbase = 0;
#pragma unroll
  for (int i = 0; i < 16; ++i) wbase += (i < w) ? wtot[i] : 0;
  int running = wbase;
  for (int j = 0; j < 52; ++j) {
    int idx = rb + j * 64 + lane;
    int v = counts[idx];
    int incl = v;
#pragma unroll
    for (int d = 1; d < 64; d <<= 1) {
      int u = __shfl_up(incl, d);
      if (lane >= d) incl += u;
    }
    if (idx < n) row_ptr[idx + 1] = running + incl;
    running += __shfl(incl, 63);
  }
  if (t == 0) row_ptr[0] = 0;
  __syncthreads();
  // ---- phase 2: exclusive scan of 8192 bins (8 per thread) ----
  int b8 = t * 8;
  int h[8];
  int ts = 0;
#pragma unroll
  for (int j = 0; j < 8; ++j) { h[j] = dhist[b8 + j]; ts += h[j]; }
  int incl = ts;
#pragma unroll
  for (int d = 1; d < 64; d <<= 1) {
    int u = __shfl_up(incl, d);
    if (lane >= d) incl += u;
  }
  if (lane == 63) wtot[w] = incl;
  __syncthreads();
  int wb2 = 0;
#pragma unroll
  for (int i = 0; i < 16; ++i) wb2 += (i < w) ? wtot[i] : 0;
  int ex = wb2 + incl - ts;
#pragma unroll
  for (int j = 0; j < 8; ++j) { dcur[b8 + j] = ex; ex += h[j]; }
}

// ============ merged setup: LPT place + CSR place + converts ===============
// blocks [0,196): node_order placement; [196,3321): col_src placement;
// [3321,3327): W transpose/convert; [3327,6452): x convert.
__global__ __launch_bounds__(256) void k_setup(const int* __restrict__ src,
        const int* __restrict__ dst, const int* __restrict__ rank,
        const int* __restrict__ row_ptr, const int* __restrict__ counts,
        int* __restrict__ dcur, int* __restrict__ node_order,
        int* __restrict__ col_src, const float* __restrict__ x,
        const float* __restrict__ Wl, const float* __restrict__ Wr,
        unsigned short* __restrict__ xb, unsigned short* __restrict__ wt,
        int n, int E, int total8) {
  int b = blockIdx.x;
  if (b < NB_NODE) {
    int i = b * 256 + threadIdx.x;
    if (i >= n) return;
    int d = counts[i];
    if (d > 127) d = 127;
    int pos = atomicAdd(&dcur[((127 - d) << 6) | (i & (DSUB - 1))], 1);
    node_order[pos] = i;
  } else if (b < NB_NODE + NB_EDGE) {
    int e = (b - NB_NODE) * 256 + threadIdx.x;
    if (e >= E) return;
    col_src[row_ptr[dst[e]] + rank[e]] = src[e];
  } else if (b < NB_NODE + NB_EDGE + 6) {
    int ls = b - NB_NODE - NB_EDGE;       // layer*2 + side
    int l = ls >> 1, s = ls & 1;
    const float* W = (s ? Wr : Wl) + l * D * D;
    unsigned short* o = wt + ls * D * D;
    for (int it = 0; it < 64; ++it) {
      int idx = it * 256 + threadIdx.x;
      int k = idx >> 7, c = idx & 127;
      o[c * D + k] = f2bf(W[idx]);        // transposed, K-contiguous
    }
  } else {
    int i = (b - NB_NODE - NB_EDGE - 6) * 256 + threadIdx.x;
    if (i >= total8) return;
    float4 a = ((const float4*)x)[2 * i];
    float4 bb = ((const float4*)x)[2 * i + 1];
    uint4 pk;
    pk.x = (unsigned)f2bf(a.x) | ((unsigned)f2bf(a.y) << 16);
    pk.y = (unsigned)f2bf(a.z) | ((unsigned)f2bf(a.w) << 16);
    pk.z = (unsigned)f2bf(bb.x) | ((unsigned)f2bf(bb.y) << 16);
    pk.w = (unsigned)f2bf(bb.z) | ((unsigned)f2bf(bb.w) << 16);
    ((uint4*)xb)[i] = pk;
  }
}

// ============ GEMM: bf16 MFMA 16x16x32 =====================================
// Block (0,0) additionally zeroes sums64 for this layer's BN accumulation.
__global__ __launch_bounds__(256) void k_gemm(const unsigned short* __restrict__ xb,
        const unsigned short* __restrict__ wt,   // this layer: [2][128 col][128 k]
        unsigned short* __restrict__ xlb, unsigned short* __restrict__ xrb,
        float* __restrict__ sums64, int n) {
  __shared__ unsigned short xs[128 * 128];   // 32 KB
  const int t = threadIdx.x;
  const int row0 = blockIdx.x * 128;
  const unsigned short* __restrict__ W = wt + (size_t)blockIdx.y * (D * D);
  unsigned short* __restrict__ outp = blockIdx.y ? xrb : xlb;

  if (blockIdx.x == 0 && blockIdx.y == 0) {
#pragma unroll
    for (int i = 0; i < SUM_SLOTS; ++i) sums64[i * 256 + t] = 0.f;
  }

#pragma unroll
  for (int i = 0; i < 8; ++i) {
    int ci = i * 256 + t;          // 16B-chunk index 0..2047
    int lr = ci >> 4, p = ci & 15;
    int grow = row0 + lr;
    if (grow >= n) grow = n - 1;   // clamped rows are never stored
    int gp = p ^ (lr & 7);
    uint4 v = *(const uint4*)(xb + (size_t)grow * D + gp * 8);
    *(uint4*)((char*)xs + ci * 16) = v;
  }
  __syncthreads();

  const int lane = t & 63, wv = t >> 6;
  const int colg = lane & 15, kg = lane >> 4;

  f32x4 acc[2][8];
#pragma unroll
  for (int rr = 0; rr < 2; ++rr)
#pragma unroll
    for (int cc = 0; cc < 8; ++cc) acc[rr][cc] = (f32x4)(0.f);

#pragma unroll
  for (int ks = 0; ks < 4; ++ks) {
    bf16x8 a[2], b[8];
#pragma unroll
    for (int rr = 0; rr < 2; ++rr) {
      int lr = wv * 32 + rr * 16 + colg;
      int byte = (lr * 256 + ks * 64 + kg * 16) ^ ((lr & 7) << 4);
      a[rr] = *(const bf16x8*)((const char*)xs + byte);
    }
#pragma unroll
    for (int cc = 0; cc < 8; ++cc) {
      int col = cc * 16 + colg;
      b[cc] = *(const bf16x8*)(W + (size_t)col * D + ks * 32 + kg * 8);
    }
#pragma unroll
    for (int rr = 0; rr < 2; ++rr)
#pragma unroll
      for (int cc = 0; cc < 8; ++cc)
        acc[rr][cc] = __builtin_amdgcn_mfma_f32_16x16x32_bf16(a[rr], b[cc], acc[rr][cc], 0, 0, 0);
  }

#pragma unroll
  for (int rr = 0; rr < 2; ++rr) {
    int rbase = row0 + wv * 32 + rr * 16 + kg * 4;
#pragma unroll
    for (int cc = 0; cc < 8; ++cc) {
      int col = cc * 16 + colg;
      f32x4 v = acc[rr][cc];
#pragma unroll
      for (int r = 0; r < 4; ++r) {
        int grow = rbase + r;
        if (grow < n) outp[(size_t)grow * D + col] = f2bf(v[r]);
      }
    }
  }
}

// ============ fused score + online-softmax + aggregate + BN partials =======
// Round-21 lesson: dropping the online-max branch raised VGPR 48->76 and
// dropped occupancy 39%->25% (compiler pipelined harder), NET LOSS in this
// latency-bound gather loop. Keep the proven online-max form (48 VGPR).

__device__ __forceinline__ void agg_step(ushort8_t hv, const float* xrv,
        const float* atv, float& m, float& den, float* ac) {
  float v[8];
#pragma unroll
  for (int j = 0; j < 8; ++j) v[j] = bf2f(hv[j]);
  float p = 0.f;
#pragma unroll
  for (int j = 0; j < 8; ++j) {
    float tt = v[j] + xrv[j];
    tt = tt > 0.f ? tt : NEG_SLOPE * tt;
    p += tt * atv[j];
  }
  p += __shfl_xor(p, 1);
  p += __shfl_xor(p, 2);
  p += __shfl_xor(p, 4);
  p += __shfl_xor(p, 8);
  if (p > m) {
    float sc = __expf(m - p);
    den *= sc;
#pragma unroll
    for (int j = 0; j < 8; ++j) ac[j] *= sc;
    m = p;
  }
  float a = __expf(p - m);
  den += a;
#pragma unroll
  for (int j = 0; j < 8; ++j) ac[j] += a * v[j];
}

__global__ __launch_bounds__(256) void k_agg(const unsigned short* __restrict__ xlb,
        const unsigned short* __restrict__ xrb, const int* __restrict__ col_src,
        const int* __restrict__ row_ptr, const int* __restrict__ node_order,
        const float* __restrict__ att, float* __restrict__ out,
        float* __restrict__ sums64, int n) {
  __shared__ float lsum[16][128];
  __shared__ float lsq[16][128];
  int g = blockIdx.x * 16 + (threadIdx.x >> 4);
  int grp = threadIdx.x >> 4;
  int lane = threadIdx.x & 15;
  bool active = (g < n);
  float r[8];
#pragma unroll
  for (int j = 0; j < 8; ++j) r[j] = 0.f;

  if (active) {
    int node = node_order[g];
    int ro = lane * 2;
    ushort8_t hr = ((const ushort8_t*)(xrb + (size_t)node * D))[lane];
    float xrv[8];
#pragma unroll
    for (int j = 0; j < 8; ++j) xrv[j] = bf2f(hr[j]);
    float4 at0 = ((const float4*)att)[ro];
    float4 at1 = ((const float4*)att)[ro + 1];
    float atv[8] = {at0.x, at0.y, at0.z, at0.w, at1.x, at1.y, at1.z, at1.w};

    int k0 = row_ptr[node], k1 = row_ptr[node + 1];
    float m = -1e30f, den = 0.f;
    float ac[8];
#pragma unroll
    for (int j = 0; j < 8; ++j) ac[j] = 0.f;

    const ushort8_t* xl8 = (const ushort8_t*)xlb;
    int k = k0;
    for (; k + 8 <= k1; k += 8) {
      int s0 = col_src[k],     s1 = col_src[k + 1], s2 = col_src[k + 2], s3 = col_src[k + 3];
      int s4 = col_src[k + 4], s5 = col_src[k + 5], s6 = col_src[k + 6], s7 = col_src[k + 7];
      ushort8_t h0 = xl8[(size_t)s0 * 16 + lane];
      ushort8_t h1 = xl8[(size_t)s1 * 16 + lane];
      ushort8_t h2 = xl8[(size_t)s2 * 16 + lane];
      ushort8_t h3 = xl8[(size_t)s3 * 16 + lane];
      ushort8_t h4 = xl8[(size_t)s4 * 16 + lane];
      ushort8_t h5 = xl8[(size_t)s5 * 16 + lane];
      ushort8_t h6 = xl8[(size_t)s6 * 16 + lane];
      ushort8_t h7 = xl8[(size_t)s7 * 16 + lane];
      agg_step(h0, xrv, atv, m, den, ac);
      agg_step(h1, xrv, atv, m, den, ac);
      agg_step(h2, xrv, atv, m, den, ac);
      agg_step(h3, xrv, atv, m, den, ac);
      agg_step(h4, xrv, atv, m, den, ac);
      agg_step(h5, xrv, atv, m, den, ac);
      agg_step(h6, xrv, atv, m, den, ac);
      agg_step(h7, xrv, atv, m, den, ac);
    }
    if (k + 4 <= k1) {
      int s0 = col_src[k], s1 = col_src[k + 1], s2 = col_src[k + 2], s3 = col_src[k + 3];
      ushort8_t h0 = xl8[(size_t)s0 * 16 + lane];
      ushort8_t h1 = xl8[(size_t)s1 * 16 + lane];
      ushort8_t h2 = xl8[(size_t)s2 * 16 + lane];
      ushort8_t h3 = xl8[(size_t)s3 * 16 + lane];
      agg_step(h0, xrv, atv, m, den, ac);
      agg_step(h1, xrv, atv, m, den, ac);
      agg_step(h2, xrv, atv, m, den, ac);
      agg_step(h3, xrv, atv, m, den, ac);
      k += 4;
    }
    for (; k < k1; ++k) {
      int s = col_src[k];
      ushort8_t h = xl8[(size_t)s * 16 + lane];
      agg_step(h, xrv, atv, m, den, ac);
    }

    float inv = 1.f / (den + 1e-16f);
#pragma unroll
    for (int j = 0; j < 8; ++j) r[j] = ac[j] * inv;
    float4* o4 = (float4*)out;
    o4[(size_t)node * 32 + ro]     = make_float4(r[0], r[1], r[2], r[3]);
    o4[(size_t)node * 32 + ro + 1] = make_float4(r[4], r[5], r[6], r[7]);
  }

  // ---- BN partials: LDS reduce 16 rows, one atomic record per block ----
#pragma unroll
  for (int j = 0; j < 8; ++j) {
    lsum[grp][lane * 8 + j] = r[j];
    lsq[grp][lane * 8 + j] = r[j] * r[j];
  }
  __syncthreads();
  int t = threadIdx.x;
  float s = 0.f;
  if (t < 128) {
#pragma unroll
    for (int gg = 0; gg < 16; ++gg) s += lsum[gg][t];
  } else {
#pragma unroll
    for (int gg = 0; gg < 16; ++gg) s += lsq[gg][t - 128];
  }
  atomicAdd(&sums64[(blockIdx.x & (SUM_SLOTS - 1)) * 256 + t], s);
}

// ============ BatchNorm finalize + apply (fused, grid-stride) ==============
__global__ __launch_bounds__(256) void k_bn_apply(const float* __restrict__ agg,
        const float* __restrict__ sums64, const float* __restrict__ gamma,
        const float* __restrict__ beta, float* __restrict__ xo,
        unsigned short* __restrict__ xbo, float inv_n, int total4, int last) {
  __shared__ float totl[256];
  __shared__ float ssl[256];
  int t = threadIdx.x;
  float a0 = 0.f, a1 = 0.f, a2 = 0.f, a3 = 0.f;
#pragma unroll
  for (int k = 0; k < SUM_SLOTS; k += 4) {
    a0 += sums64[(k + 0) * 256 + t];
    a1 += sums64[(k + 1) * 256 + t];
    a2 += sums64[(k + 2) * 256 + t];
    a3 += sums64[(k + 3) * 256 + t];
  }
  totl[t] = (a0 + a1) + (a2 + a3);
  __syncthreads();
  if (t < 128) {
    float mu = totl[t] * inv_n;
    float var = totl[128 + t] * inv_n - mu * mu;
    float rs = rsqrtf(var + BN_EPS);
    float sc = gamma[t] * rs;
    ssl[t] = sc;
    ssl[128 + t] = beta[t] - mu * sc;
  }
  __syncthreads();

  for (int i = blockIdx.x * 256 + t; i < total4; i += gridDim.x * 256) {
    float4 v = ((const float4*)agg)[i];
    int c4 = i & (D / 4 - 1);
    float4 sc = ((const float4*)ssl)[c4];
    float4 sh = ((const float4*)ssl)[D / 4 + c4];
    float y0 = sc.x * v.x + sh.x;
    float y1 = sc.y * v.y + sh.y;
    float y2 = sc.z * v.z + sh.z;
    float y3 = sc.w * v.w + sh.w;
    float4 g;
    g.x = 0.5f * y0 * (1.f + erff(y0 * 0.70710678118654752f));
    g.y = 0.5f * y1 * (1.f + erff(y1 * 0.70710678118654752f));
    g.z = 0.5f * y2 * (1.f + erff(y2 * 0.70710678118654752f));
    g.w = 0.5f * y3 * (1.f + erff(y3 * 0.70710678118654752f));
    if (last) {
      ((float4*)xo)[i] = g;
    } else {
      uint2 pk;
      pk.x = (unsigned)f2bf(g.x) | ((unsigned)f2bf(g.y) << 16);
      pk.y = (unsigned)f2bf(g.z) | ((unsigned)f2bf(g.w) << 16);
      ((uint2*)xbo)[i] = pk;
    }
  }
}

// ===========================================================================

extern "C" void kernel_launch(void* const* d_in, const int* in_sizes, int n_in,
                              void* d_out, int out_size, void* d_ws, size_t ws_size,
                              hipStream_t stream) {
  const float* x0    = (const float*)d_in[0];
  const int*   ei    = (const int*)d_in[1];
  const float* Wl    = (const float*)d_in[2];
  const float* Wr    = (const float*)d_in[3];
  const float* att   = (const float*)d_in[4];
  // d_in[5] = bias: cancelled exactly by BatchNorm mean-subtraction; unused.
  const float* gamma = (const float*)d_in[6];
  const float* beta  = (const float*)d_in[7];
  float* out = (float*)d_out;

  float* ws = (float*)d_ws;
  unsigned short* xb  = (unsigned short*)ws;              // [N][128] bf16
  unsigned short* xlb = (unsigned short*)(ws + 3200000);  // [N][128] bf16
  unsigned short* xrb = (unsigned short*)(ws + 6400000);  // [N][128] bf16
  int*   col_src    = (int*)(ws + 9600000);       //   800,000
  int*   rank       = (int*)(ws + 10400000);      //   800,000
  int*   row_ptr    = (int*)(ws + 11200000);      //    50,001
  int*   counts     = (int*)(ws + 11250004);      // COUNTS_PAD (53,248)
  int*   dhist      = (int*)(ws + 11303252);      //     8,192 (adjacent to counts)
  int*   dcur       = (int*)(ws + 11311444);      //     8,192
  int*   node_order = (int*)(ws + 11319636);      //    50,000
  float* sums64     = ws + 11369636;              //    16,384 (64 x 256)
  unsigned short* wt = (unsigned short*)(ws + 11386020);  // [3][2][128][128] bf16

  const int* src = ei;
  const int* dst = ei + NEDGES;

  // ---- one-time: CSR build + LPT sort + merged setup (5 dispatches) ----
  hipMemsetAsync(counts, 0, (COUNTS_PAD + DBINS) * sizeof(int), stream);  // counts+dhist
  k_rank<<<(NEDGES + 255) / 256, 256, 0, stream>>>(dst, counts, rank, NEDGES);
  k_deg_hist<<<(NNODES + 255) / 256, 256, 0, stream>>>(counts, dhist, NNODES);
  k_scan_sort<<<1, SCAN_THREADS, 0, stream>>>(counts, dhist, row_ptr, dcur, NNODES);
  k_setup<<<NB_NODE + NB_EDGE + 6 + NB_X, 256, 0, stream>>>(
      src, dst, rank, row_ptr, counts, dcur, node_order, col_src,
      x0, Wl, Wr, xb, wt, NNODES, NEDGES, NNODES * (D / 8));

  dim3 ggrid((NNODES + 127) / 128, 2);

  for (int l = 0; l < 3; ++l) {
    k_gemm<<<ggrid, 256, 0, stream>>>(xb, wt + (size_t)l * 2 * D * D, xlb, xrb,
                                      sums64, NNODES);

    // d_out is dead as an input after k_gemm -> safe to overwrite with agg.
    k_agg<<<(NNODES + 15) / 16, 256, 0, stream>>>(xlb, xrb, col_src, row_ptr,
                                                  node_order, att + l * D, out,
                                                  sums64, NNODES);

    k_bn_apply<<<512, 256, 0, stream>>>(out, sums64, gamma + l * D, beta + l * D,
                                        out, xb, 1.0f / NNODES,
                                        NNODES * (D / 4), l == 2 ? 1 : 0);
  }
}